// Round 9
// baseline (39.926 us; speedup 1.0000x reference)
//
#include <hip/hip_runtime.h>
#include <math.h>

#define HALF_PI   1.57079632679489662f
#define INV_SQRT2 0.70710678118654752f
#define NPART     1024   // edge-kernel blocks; strided EPT=4 covers E <= 1048576

// ---------------------------------------------------------------------------
// K1: node projections + ALL trig. One node per wave per iteration.
// Lane l holds feat[n][4l..4l+3]; weight fragments preloaded (32 VGPRs).
// Multi-value butterfly reduce (10 shuffles/node) leaves dot[g] in lane
// group g = lane>>3. Group leaders apply bias+tanh+sincos and store the
// POST-TRIG values:
//   qtab[n] (32B): per wire w, u_w = ( (c+s)/sqrt2, (c-s)/sqrt2 )  [H*RY|0>]
//   ktab[n] (32B): per wire w, ( sin(k/2), cos(k/2) )              [CRY terms]
// This moves 16 trans-ops/edge -> 2 trans-ops/node (16x fewer).
// ---------------------------------------------------------------------------
__global__ __launch_bounds__(256) void node_qk(
        const float* __restrict__ feat,
        const float* __restrict__ Wq, const float* __restrict__ bq,
        const float* __restrict__ Wk, const float* __restrict__ bk,
        float2* __restrict__ qtab, float2* __restrict__ ktab, int N) {
    const int lane  = threadIdx.x & 63;
    const int wid   = (int)((blockIdx.x * blockDim.x + threadIdx.x) >> 6);
    const int nwid  = (int)((gridDim.x * blockDim.x) >> 6);

    float4 wq4[4], wk4[4];
    #pragma unroll
    for (int q = 0; q < 4; ++q) {
        wq4[q] = reinterpret_cast<const float4*>(Wq + q * 256)[lane];
        wk4[q] = reinterpret_cast<const float4*>(Wk + q * 256)[lane];
    }
    const int  g    = lane >> 3;
    const float bias = (g < 4) ? bq[g] : bk[g & 3];
    const bool hi  = (lane & 32) != 0;
    const bool s16 = (lane & 16) != 0;
    const bool s8  = (lane & 8)  != 0;

    for (int n = wid; n < N; n += nwid) {
        float4 f = reinterpret_cast<const float4*>(feat)[(size_t)n * 64 + lane];
        float acc[8];
        #pragma unroll
        for (int q = 0; q < 4; ++q) {
            acc[q]     = f.x * wq4[q].x + f.y * wq4[q].y + f.z * wq4[q].z + f.w * wq4[q].w;
            acc[4 + q] = f.x * wk4[q].x + f.y * wk4[q].y + f.z * wk4[q].z + f.w * wk4[q].w;
        }
        // multi-value butterfly: 10 shuffles per node
        #pragma unroll
        for (int j = 0; j < 4; ++j) {
            float give = hi ? acc[j] : acc[j + 4];
            float r = __shfl_xor(give, 32, 64);
            acc[j]     += hi ? 0.f : r;
            acc[j + 4] += hi ? r : 0.f;
        }
        #pragma unroll
        for (int j = 0; j < 2; ++j) {
            float giveLow  = hi ? acc[6 + j] : acc[2 + j];
            float giveHigh = hi ? acc[4 + j] : acc[j];
            float give = s16 ? giveHigh : giveLow;
            float r = __shfl_xor(give, 16, 64);
            acc[j]     += (!hi && !s16) ? r : 0.f;
            acc[2 + j] += (!hi &&  s16) ? r : 0.f;
            acc[4 + j] += ( hi && !s16) ? r : 0.f;
            acc[6 + j] += ( hi &&  s16) ? r : 0.f;
        }
        float a_even = hi ? (s16 ? acc[6] : acc[4]) : (s16 ? acc[2] : acc[0]);
        float a_odd  = hi ? (s16 ? acc[7] : acc[5]) : (s16 ? acc[3] : acc[1]);
        float give3 = s8 ? a_even : a_odd;
        float r3 = __shfl_xor(give3, 8, 64);
        float v = (s8 ? a_odd : a_even) + r3;
        v += __shfl_xor(v, 4, 64);
        v += __shfl_xor(v, 2, 64);
        v += __shfl_xor(v, 1, 64);

        if ((lane & 7) == 0) {
            float t = tanhf(v + bias) * HALF_PI;
            float s, c;
            __sincosf(t * 0.5f, &s, &c);
            if (g < 4)
                qtab[(size_t)n * 4 + g] =
                    make_float2((c + s) * INV_SQRT2, (c - s) * INV_SQRT2);
            else
                ktab[(size_t)n * 4 + (g & 3)] = make_float2(s, c);
        }
    }
}

// ---------------------------------------------------------------------------
// 4-qubit real circuit from PRE-TRIG'd node data. qa/qb = u values (4 wires),
// ka/kb = (si,co) per wire. ~210 VALU + 1 trans op.
// ---------------------------------------------------------------------------
__device__ __forceinline__ float edge_ex(float4 qa, float4 qb,
                                         float4 ka, float4 kb,
                                         const float* scz, const float* scx) {
    // product state, wire 0 = MSB: a[x] = c01[x>>2] * c23[x&3]
    float c01[4] = {qa.x * qa.z, qa.x * qa.w, qa.y * qa.z, qa.y * qa.w};
    float c23[4] = {qb.x * qb.z, qb.x * qb.w, qb.y * qb.z, qb.y * qb.w};
    float a[16];
    #pragma unroll
    for (int x = 0; x < 16; ++x) a[x] = c01[x >> 2] * c23[x & 3];

    // CRY(k_w) on (w, (w+1)%4); (si,co) precomputed
    const float sic[4][2] = {{ka.x, ka.y}, {ka.z, ka.w}, {kb.x, kb.y}, {kb.z, kb.w}};
    #pragma unroll
    for (int w = 0; w < 4; ++w) {
        const float si = sic[w][0], co = sic[w][1];
        const int cb = 1 << (3 - w);
        const int tb = 1 << (3 - ((w + 1) & 3));
        #pragma unroll
        for (int x = 0; x < 16; ++x) {
            if ((x & cb) && !(x & tb)) {
                float a0 = a[x], a1 = a[x | tb];
                a[x]      = co * a0 - si * a1;
                a[x | tb] = si * a0 + co * a1;
            }
        }
    }

    float p[16];
    #pragma unroll
    for (int x = 0; x < 16; ++x) p[x] = a[x] * a[x];

    float attn = 0.f;
    #pragma unroll
    for (int q = 0; q < 4; ++q) {
        const int bit = 1 << (3 - q);
        float sz = 0.f, sx = 0.f;
        #pragma unroll
        for (int x = 0; x < 16; ++x) {
            sz += (x & bit) ? -p[x] : p[x];
            if (!(x & bit)) sx += a[x] * a[x | bit];
        }
        attn += scz[q] * sz - scx[q] * (2.f * sx);
    }
    return __expf(attn * 0.25f);
}

// ---------------------------------------------------------------------------
// K2: per-edge circuit, STRIDED 4 edges/thread (balanced across all 1024
// blocks). All index loads + all 16 gathers (2x32B per endpoint) issued
// up-front; bound-clamped indices avoid divergent gather branches.
// Deterministic per-block partial sums.
// ---------------------------------------------------------------------------
__global__ __launch_bounds__(256, 4) void edge_attn(
        const int* __restrict__ ei,
        const float4* __restrict__ qtab, const float4* __restrict__ ktab,
        const float* __restrict__ qp,
        float* __restrict__ out, float* __restrict__ partial, int E) {
    __shared__ float scz[4], scx[4];
    __shared__ float red[256];
    const int tid = threadIdx.x;
    if (tid < 4) {
        float phi = qp[3 * tid + 0];
        float th  = qp[3 * tid + 1];
        float sth, cth;
        sincosf(th, &sth, &cth);
        scz[tid] = cth;
        scx[tid] = sth * cosf(phi);
    }
    __syncthreads();

    const int gtid  = blockIdx.x * 256 + tid;
    const int total = NPART * 256;

    int   sidx[4], didx[4];
    bool  val[4];
    #pragma unroll
    for (int it = 0; it < 4; ++it) {
        const int e  = gtid + it * total;
        const int ee = (e < E) ? e : (E - 1);
        val[it]  = (e < E);
        sidx[it] = ei[ee];
        didx[it] = ei[E + ee];
    }
    float4 qa[4], qb[4], ka[4], kb[4];
    #pragma unroll
    for (int it = 0; it < 4; ++it) {
        qa[it] = qtab[2 * sidx[it]];
        qb[it] = qtab[2 * sidx[it] + 1];
        ka[it] = ktab[2 * didx[it]];
        kb[it] = ktab[2 * didx[it] + 1];
    }

    float lsum = 0.f;
    #pragma unroll
    for (int it = 0; it < 4; ++it) {
        const int e = gtid + it * total;
        if (val[it]) {
            float v = edge_ex(qa[it], qb[it], ka[it], kb[it], scz, scx);
            out[e] = v;
            lsum += v;
        }
    }

    red[tid] = lsum;
    __syncthreads();
    #pragma unroll
    for (int s = 128; s > 0; s >>= 1) {
        if (tid < s) red[tid] += red[tid + s];
        __syncthreads();
    }
    if (tid == 0) partial[blockIdx.x] = red[0];
}

// ---------------------------------------------------------------------------
// K3: every block redundantly tree-reduces the NPART partials in identical
// order (same float in all blocks), then normalizes its float4 slice.
// ---------------------------------------------------------------------------
__global__ __launch_bounds__(256) void normalize_out(
        float* __restrict__ out, const float* __restrict__ partial, int E) {
    __shared__ float red[256];
    const int tid = threadIdx.x;
    float s = 0.f;
    #pragma unroll
    for (int k = 0; k < NPART / 256; ++k) s += partial[tid + k * 256];
    red[tid] = s;
    __syncthreads();
    #pragma unroll
    for (int st = 128; st > 0; st >>= 1) {
        if (tid < st) red[tid] += red[tid + st];
        __syncthreads();
    }
    const float inv = 1.f / red[0];

    const int nv4    = E >> 2;
    const int stride = (int)(gridDim.x * 256);
    float4* out4 = reinterpret_cast<float4*>(out);
    for (int i = blockIdx.x * 256 + tid; i < nv4; i += stride) {
        float4 v = out4[i];
        v.x *= inv; v.y *= inv; v.z *= inv; v.w *= inv;
        out4[i] = v;
    }
    const int tail = nv4 << 2;
    for (int e = tail + blockIdx.x * 256 + tid; e < E; e += stride)
        out[e] *= inv;
}

extern "C" void kernel_launch(void* const* d_in, const int* in_sizes, int n_in,
                              void* d_out, int out_size, void* d_ws, size_t ws_size,
                              hipStream_t stream) {
    const float* feat = (const float*)d_in[0];
    const int*   ei   = (const int*)d_in[1];
    const float* Wq   = (const float*)d_in[2];
    const float* bq   = (const float*)d_in[3];
    const float* Wk   = (const float*)d_in[4];
    const float* bk   = (const float*)d_in[5];
    const float* qp   = (const float*)d_in[6];

    int D = in_sizes[2] / 4;          // 256
    int N = in_sizes[0] / D;          // 50000
    int E = in_sizes[1] / 2;          // 800000
    (void)D;

    float* ws      = (float*)d_ws;
    float* partial = ws;                         // NPART floats (4 KB)
    float* qtab    = ws + NPART;                 // 8N floats (16B aligned)
    float* ktab    = qtab + (size_t)N * 8;       // 8N floats
    float* out     = (float*)d_out;

    node_qk<<<2048, 256, 0, stream>>>(feat, Wq, bq, Wk, bk,
                                      (float2*)qtab, (float2*)ktab, N);
    edge_attn<<<NPART, 256, 0, stream>>>(ei, (const float4*)qtab, (const float4*)ktab,
                                         qp, out, partial, E);
    normalize_out<<<1024, 256, 0, stream>>>(out, partial, E);
}

// Round 10
// 34.154 us; speedup vs baseline: 1.1690x; 1.1690x over previous
//
#include <hip/hip_runtime.h>
#include <math.h>

#define HALF_PI   1.57079632679489662f
#define INV_SQRT2 0.70710678118654752f
#define NPART     1024   // edge-kernel blocks; strided EPT=4 covers E <= 1048576

// ---------------------------------------------------------------------------
// K1: node projections. TWO nodes per wave per iteration (both 1KB feature
// loads issued back-to-back for latency overlap). Weight fragments preloaded
// (32 VGPRs). Multi-value butterfly reduce: 10 shuffles per node.
// ---------------------------------------------------------------------------
__global__ __launch_bounds__(256) void node_qk(
        const float* __restrict__ feat,
        const float* __restrict__ Wq, const float* __restrict__ bq,
        const float* __restrict__ Wk, const float* __restrict__ bk,
        float* __restrict__ qtab, float* __restrict__ ktab, int N) {
    const int lane  = threadIdx.x & 63;
    const int wid   = (int)((blockIdx.x * blockDim.x + threadIdx.x) >> 6);
    const int nwid  = (int)((gridDim.x * blockDim.x) >> 6);

    float4 wq4[4], wk4[4];
    #pragma unroll
    for (int q = 0; q < 4; ++q) {
        wq4[q] = reinterpret_cast<const float4*>(Wq + q * 256)[lane];
        wk4[q] = reinterpret_cast<const float4*>(Wk + q * 256)[lane];
    }
    const int  g    = lane >> 3;
    const float bias = (g < 4) ? bq[g] : bk[g & 3];
    const bool hi  = (lane & 32) != 0;
    const bool s16 = (lane & 16) != 0;
    const bool s8  = (lane & 8)  != 0;

    for (int nb = wid * 2; nb < N; nb += nwid * 2) {
        const int  n1ok = (nb + 1 < N);
        float4 f0 = reinterpret_cast<const float4*>(feat)[(size_t)nb * 64 + lane];
        float4 f1 = n1ok ? reinterpret_cast<const float4*>(feat)[(size_t)(nb + 1) * 64 + lane]
                         : make_float4(0.f, 0.f, 0.f, 0.f);

        float acc0[8], acc1[8];
        #pragma unroll
        for (int q = 0; q < 4; ++q) {
            acc0[q]     = f0.x * wq4[q].x + f0.y * wq4[q].y + f0.z * wq4[q].z + f0.w * wq4[q].w;
            acc0[4 + q] = f0.x * wk4[q].x + f0.y * wk4[q].y + f0.z * wk4[q].z + f0.w * wk4[q].w;
            acc1[q]     = f1.x * wq4[q].x + f1.y * wq4[q].y + f1.z * wq4[q].z + f1.w * wq4[q].w;
            acc1[4 + q] = f1.x * wk4[q].x + f1.y * wk4[q].y + f1.z * wk4[q].z + f1.w * wk4[q].w;
        }

        #pragma unroll
        for (int p = 0; p < 2; ++p) {
            float* acc = (p == 0) ? acc0 : acc1;
            // multi-value butterfly: 10 shuffles per node
            #pragma unroll
            for (int j = 0; j < 4; ++j) {
                float give = hi ? acc[j] : acc[j + 4];
                float r = __shfl_xor(give, 32, 64);
                acc[j]     += hi ? 0.f : r;
                acc[j + 4] += hi ? r : 0.f;
            }
            #pragma unroll
            for (int j = 0; j < 2; ++j) {
                float giveLow  = hi ? acc[6 + j] : acc[2 + j];
                float giveHigh = hi ? acc[4 + j] : acc[j];
                float give = s16 ? giveHigh : giveLow;
                float r = __shfl_xor(give, 16, 64);
                acc[j]     += (!hi && !s16) ? r : 0.f;
                acc[2 + j] += (!hi &&  s16) ? r : 0.f;
                acc[4 + j] += ( hi && !s16) ? r : 0.f;
                acc[6 + j] += ( hi &&  s16) ? r : 0.f;
            }
            float a_even = hi ? (s16 ? acc[6] : acc[4]) : (s16 ? acc[2] : acc[0]);
            float a_odd  = hi ? (s16 ? acc[7] : acc[5]) : (s16 ? acc[3] : acc[1]);
            float give3 = s8 ? a_even : a_odd;
            float r3 = __shfl_xor(give3, 8, 64);
            float v = (s8 ? a_odd : a_even) + r3;
            v += __shfl_xor(v, 4, 64);
            v += __shfl_xor(v, 2, 64);
            v += __shfl_xor(v, 1, 64);

            const int n = nb + p;
            if ((p == 0 || n1ok) && (lane & 7) == 0) {
                float t = tanhf(v + bias) * HALF_PI;
                if (g < 4) qtab[(size_t)n * 4 + g] = t;
                else       ktab[(size_t)n * 4 + (g & 3)] = t;
            }
        }
    }
}

// 4-qubit real circuit for one edge: returns exp(attn/4)
__device__ __forceinline__ float edge_ex(float4 qv, float4 kv,
                                         const float* scz, const float* scx) {
    float qa[4] = {qv.x, qv.y, qv.z, qv.w};
    float ka[4] = {kv.x, kv.y, kv.z, kv.w};
    float u[4][2];
    #pragma unroll
    for (int w = 0; w < 4; ++w) {
        float s, c;
        __sincosf(qa[w] * 0.5f, &s, &c);
        u[w][0] = (c + s) * INV_SQRT2;
        u[w][1] = (c - s) * INV_SQRT2;
    }
    float a[16];
    #pragma unroll
    for (int x = 0; x < 16; ++x)
        a[x] = u[0][(x >> 3) & 1] * u[1][(x >> 2) & 1] *
               u[2][(x >> 1) & 1] * u[3][x & 1];
    #pragma unroll
    for (int w = 0; w < 4; ++w) {
        float si, co;
        __sincosf(ka[w] * 0.5f, &si, &co);
        const int cb = 1 << (3 - w);
        const int tb = 1 << (3 - ((w + 1) & 3));
        #pragma unroll
        for (int x = 0; x < 16; ++x) {
            if ((x & cb) && !(x & tb)) {
                float a0 = a[x], a1 = a[x | tb];
                a[x]      = co * a0 - si * a1;
                a[x | tb] = si * a0 + co * a1;
            }
        }
    }
    float attn = 0.f;
    #pragma unroll
    for (int q = 0; q < 4; ++q) {
        const int bit = 1 << (3 - q);
        float sz = 0.f, sx = 0.f;
        #pragma unroll
        for (int x = 0; x < 16; ++x) {
            float pp = a[x] * a[x];
            sz += (x & bit) ? -pp : pp;
            if (!(x & bit)) sx += a[x] * a[x | bit];
        }
        attn += scz[q] * sz - scx[q] * (2.f * sx);
    }
    return __expf(attn * 0.25f);
}

// ---------------------------------------------------------------------------
// K2: per-edge circuit, STRIDED 4 edges/thread (balanced). Index loads
// prefetched up-front (8 VGPRs, clamped); table gathers inline per edge
// (R4-proven — no big staging, no VGPR cap). Deterministic block partials.
// ---------------------------------------------------------------------------
__global__ __launch_bounds__(256) void edge_attn(
        const int* __restrict__ ei,
        const float4* __restrict__ qtab, const float4* __restrict__ ktab,
        const float* __restrict__ qp,
        float* __restrict__ out, float* __restrict__ partial, int E) {
    __shared__ float scz[4], scx[4];
    __shared__ float red[256];
    const int tid = threadIdx.x;
    if (tid < 4) {
        float phi = qp[3 * tid + 0];
        float th  = qp[3 * tid + 1];
        float sth, cth;
        sincosf(th, &sth, &cth);
        scz[tid] = cth;
        scx[tid] = sth * cosf(phi);
    }
    __syncthreads();

    const int gtid  = blockIdx.x * 256 + tid;
    const int total = NPART * 256;

    int sidx[4], didx[4];
    #pragma unroll
    for (int it = 0; it < 4; ++it) {
        const int e  = gtid + it * total;
        const int ee = (e < E) ? e : (E - 1);
        sidx[it] = ei[ee];
        didx[it] = ei[E + ee];
    }

    float lsum = 0.f;
    #pragma unroll
    for (int it = 0; it < 4; ++it) {
        const int e = gtid + it * total;
        if (e < E) {
            float v = edge_ex(qtab[sidx[it]], ktab[didx[it]], scz, scx);
            out[e] = v;
            lsum += v;
        }
    }

    red[tid] = lsum;
    __syncthreads();
    #pragma unroll
    for (int s = 128; s > 0; s >>= 1) {
        if (tid < s) red[tid] += red[tid + s];
        __syncthreads();
    }
    if (tid == 0) partial[blockIdx.x] = red[0];
}

// ---------------------------------------------------------------------------
// K3: every block redundantly tree-reduces the NPART partials in identical
// order (same float in all blocks), then normalizes its float4 slice.
// ---------------------------------------------------------------------------
__global__ __launch_bounds__(256) void normalize_out(
        float* __restrict__ out, const float* __restrict__ partial, int E) {
    __shared__ float red[256];
    const int tid = threadIdx.x;
    float s = 0.f;
    #pragma unroll
    for (int k = 0; k < NPART / 256; ++k) s += partial[tid + k * 256];
    red[tid] = s;
    __syncthreads();
    #pragma unroll
    for (int st = 128; st > 0; st >>= 1) {
        if (tid < st) red[tid] += red[tid + st];
        __syncthreads();
    }
    const float inv = 1.f / red[0];

    const int nv4    = E >> 2;
    const int stride = (int)(gridDim.x * 256);
    float4* out4 = reinterpret_cast<float4*>(out);
    for (int i = blockIdx.x * 256 + tid; i < nv4; i += stride) {
        float4 v = out4[i];
        v.x *= inv; v.y *= inv; v.z *= inv; v.w *= inv;
        out4[i] = v;
    }
    const int tail = nv4 << 2;
    for (int e = tail + blockIdx.x * 256 + tid; e < E; e += stride)
        out[e] *= inv;
}

extern "C" void kernel_launch(void* const* d_in, const int* in_sizes, int n_in,
                              void* d_out, int out_size, void* d_ws, size_t ws_size,
                              hipStream_t stream) {
    const float* feat = (const float*)d_in[0];
    const int*   ei   = (const int*)d_in[1];
    const float* Wq   = (const float*)d_in[2];
    const float* bq   = (const float*)d_in[3];
    const float* Wk   = (const float*)d_in[4];
    const float* bk   = (const float*)d_in[5];
    const float* qp   = (const float*)d_in[6];

    int D = in_sizes[2] / 4;          // 256
    int N = in_sizes[0] / D;          // 50000
    int E = in_sizes[1] / 2;          // 800000
    (void)D;

    float* ws      = (float*)d_ws;
    float* partial = ws;                         // NPART floats (4 KB)
    float* qtab    = ws + NPART;                 // 4N floats (16B aligned)
    float* ktab    = qtab + (size_t)N * 4;       // 4N floats
    float* out     = (float*)d_out;

    node_qk<<<2048, 256, 0, stream>>>(feat, Wq, bq, Wk, bk, qtab, ktab, N);
    edge_attn<<<NPART, 256, 0, stream>>>(ei, (const float4*)qtab, (const float4*)ktab,
                                         qp, out, partial, E);
    normalize_out<<<1024, 256, 0, stream>>>(out, partial, E);
}

// Round 11
// 32.838 us; speedup vs baseline: 1.2158x; 1.0401x over previous
//
#include <hip/hip_runtime.h>
#include <hip/hip_fp16.h>
#include <math.h>

#define HALF_PI   1.57079632679489662f
#define INV_SQRT2 0.70710678118654752f
#define NPART     1024   // edge-kernel blocks; strided EPT=4 covers E <= 1048576

// ---------------------------------------------------------------------------
// K1: node projections. TWO nodes per wave per iteration (both 1KB feature
// loads issued back-to-back). Weight fragments preloaded (32 VGPRs).
// Multi-value butterfly reduce: 10 shuffles per node. (R4/R10-proven)
// ---------------------------------------------------------------------------
__global__ __launch_bounds__(256) void node_qk(
        const float* __restrict__ feat,
        const float* __restrict__ Wq, const float* __restrict__ bq,
        const float* __restrict__ Wk, const float* __restrict__ bk,
        float* __restrict__ qtab, float* __restrict__ ktab, int N) {
    const int lane  = threadIdx.x & 63;
    const int wid   = (int)((blockIdx.x * blockDim.x + threadIdx.x) >> 6);
    const int nwid  = (int)((gridDim.x * blockDim.x) >> 6);

    float4 wq4[4], wk4[4];
    #pragma unroll
    for (int q = 0; q < 4; ++q) {
        wq4[q] = reinterpret_cast<const float4*>(Wq + q * 256)[lane];
        wk4[q] = reinterpret_cast<const float4*>(Wk + q * 256)[lane];
    }
    const int  g    = lane >> 3;
    const float bias = (g < 4) ? bq[g] : bk[g & 3];
    const bool hi  = (lane & 32) != 0;
    const bool s16 = (lane & 16) != 0;
    const bool s8  = (lane & 8)  != 0;

    for (int nb = wid * 2; nb < N; nb += nwid * 2) {
        const int  n1ok = (nb + 1 < N);
        float4 f0 = reinterpret_cast<const float4*>(feat)[(size_t)nb * 64 + lane];
        float4 f1 = n1ok ? reinterpret_cast<const float4*>(feat)[(size_t)(nb + 1) * 64 + lane]
                         : make_float4(0.f, 0.f, 0.f, 0.f);

        float acc0[8], acc1[8];
        #pragma unroll
        for (int q = 0; q < 4; ++q) {
            acc0[q]     = f0.x * wq4[q].x + f0.y * wq4[q].y + f0.z * wq4[q].z + f0.w * wq4[q].w;
            acc0[4 + q] = f0.x * wk4[q].x + f0.y * wk4[q].y + f0.z * wk4[q].z + f0.w * wk4[q].w;
            acc1[q]     = f1.x * wq4[q].x + f1.y * wq4[q].y + f1.z * wq4[q].z + f1.w * wq4[q].w;
            acc1[4 + q] = f1.x * wk4[q].x + f1.y * wk4[q].y + f1.z * wk4[q].z + f1.w * wk4[q].w;
        }

        #pragma unroll
        for (int p = 0; p < 2; ++p) {
            float* acc = (p == 0) ? acc0 : acc1;
            #pragma unroll
            for (int j = 0; j < 4; ++j) {
                float give = hi ? acc[j] : acc[j + 4];
                float r = __shfl_xor(give, 32, 64);
                acc[j]     += hi ? 0.f : r;
                acc[j + 4] += hi ? r : 0.f;
            }
            #pragma unroll
            for (int j = 0; j < 2; ++j) {
                float giveLow  = hi ? acc[6 + j] : acc[2 + j];
                float giveHigh = hi ? acc[4 + j] : acc[j];
                float give = s16 ? giveHigh : giveLow;
                float r = __shfl_xor(give, 16, 64);
                acc[j]     += (!hi && !s16) ? r : 0.f;
                acc[2 + j] += (!hi &&  s16) ? r : 0.f;
                acc[4 + j] += ( hi && !s16) ? r : 0.f;
                acc[6 + j] += ( hi &&  s16) ? r : 0.f;
            }
            float a_even = hi ? (s16 ? acc[6] : acc[4]) : (s16 ? acc[2] : acc[0]);
            float a_odd  = hi ? (s16 ? acc[7] : acc[5]) : (s16 ? acc[3] : acc[1]);
            float give3 = s8 ? a_even : a_odd;
            float r3 = __shfl_xor(give3, 8, 64);
            float v = (s8 ? a_odd : a_even) + r3;
            v += __shfl_xor(v, 4, 64);
            v += __shfl_xor(v, 2, 64);
            v += __shfl_xor(v, 1, 64);

            const int n = nb + p;
            if ((p == 0 || n1ok) && (lane & 7) == 0) {
                float t = tanhf(v + bias) * HALF_PI;
                if (g < 4) qtab[(size_t)n * 4 + g] = t;
                else       ktab[(size_t)n * 4 + (g & 3)] = t;
            }
        }
    }
}

// ---------------------------------------------------------------------------
// 4-qubit real circuit. W[0..7] = pre-scaled Walsh weights for the Z part
// (attn_Z = sum_{x<8} W[x]*(a[x]^2 - a[15-x]^2), using W[~x] = -W[x]);
// cx[q] = -0.5*sin(th)*cos(phi)*... pre-scaled X coefficients. Returns
// exp(attn) with 0.25 already folded into W/cx.
// ---------------------------------------------------------------------------
__device__ __forceinline__ float edge_ex(float4 qv, float4 kv,
                                         const float* W, const float* cx) {
    float u[4][2];
    {
        float qa[4] = {qv.x, qv.y, qv.z, qv.w};
        #pragma unroll
        for (int w = 0; w < 4; ++w) {
            float s, c;
            __sincosf(qa[w] * 0.5f, &s, &c);
            u[w][0] = (c + s) * INV_SQRT2;
            u[w][1] = (c - s) * INV_SQRT2;
        }
    }
    // product state, wire 0 = MSB
    float c01[4] = {u[0][0]*u[1][0], u[0][0]*u[1][1], u[0][1]*u[1][0], u[0][1]*u[1][1]};
    float c23[4] = {u[2][0]*u[3][0], u[2][0]*u[3][1], u[2][1]*u[3][0], u[2][1]*u[3][1]};
    float a[16];
    #pragma unroll
    for (int x = 0; x < 16; ++x) a[x] = c01[x >> 2] * c23[x & 3];

    // CRY(k_w) on (w, (w+1)%4), (si,co) from kv angles
    {
        float ka[4] = {kv.x, kv.y, kv.z, kv.w};
        #pragma unroll
        for (int w = 0; w < 4; ++w) {
            float si, co;
            __sincosf(ka[w] * 0.5f, &si, &co);
            const int cb = 1 << (3 - w);
            const int tb = 1 << (3 - ((w + 1) & 3));
            #pragma unroll
            for (int x = 0; x < 16; ++x) {
                if ((x & cb) && !(x & tb)) {
                    float a0 = a[x], a1 = a[x | tb];
                    a[x]      = co * a0 - si * a1;
                    a[x | tb] = si * a0 + co * a1;
                }
            }
        }
    }

    // Z part via Walsh weights: 24 instr
    float attn = 0.f;
    #pragma unroll
    for (int x = 0; x < 8; ++x) {
        float pu = a[15 - x] * a[15 - x];
        float d  = __builtin_fmaf(a[x], a[x], -pu);
        attn = __builtin_fmaf(W[x], d, attn);
    }
    // X part: 4 x (8 fma + 1 fma)
    #pragma unroll
    for (int q = 0; q < 4; ++q) {
        const int bit = 1 << (3 - q);
        float sx = 0.f;
        #pragma unroll
        for (int x = 0; x < 16; ++x)
            if (!(x & bit)) sx = __builtin_fmaf(a[x], a[x | bit], sx);
        attn = __builtin_fmaf(cx[q], sx, attn);
    }
    return __expf(attn);
}

// ---------------------------------------------------------------------------
// K2: per-edge circuit, STRIDED 4 edges/thread. Index loads prefetched;
// gathers inline. Stores fp16 ex (half traffic); block partial sums use the
// ROUNDED values so K3's normalize is self-consistent.
// ---------------------------------------------------------------------------
__global__ __launch_bounds__(256) void edge_attn(
        const int* __restrict__ ei,
        const float4* __restrict__ qtab, const float4* __restrict__ ktab,
        const float* __restrict__ qp,
        __half* __restrict__ exh, float* __restrict__ partial, int E) {
    __shared__ float scz[4], scxs[4];
    __shared__ float red[256];
    const int tid = threadIdx.x;
    if (tid < 4) {
        float phi = qp[3 * tid + 0];
        float th  = qp[3 * tid + 1];
        float sth, cth;
        sincosf(th, &sth, &cth);
        scz[tid]  = 0.25f * cth;                 // 0.25 scale folded
        scxs[tid] = -0.5f * sth * cosf(phi);     // -2*scx*0.25 folded
    }
    __syncthreads();

    // per-thread Walsh weights (14 adds) + X coefficients
    const float z0 = scz[0], z1 = scz[1], z2 = scz[2], z3 = scz[3];
    const float u0 = z2 + z3, u1 = z2 - z3;
    const float w00 = z1 + u0, w01 = z1 + u1, w10 = z1 - u1, w11 = z1 - u0;
    const float W[8] = {z0 + w00, z0 + w01, z0 + w10, z0 + w11,
                        z0 - w11, z0 - w10, z0 - w01, z0 - w00};
    const float cx[4] = {scxs[0], scxs[1], scxs[2], scxs[3]};

    const int gtid  = blockIdx.x * 256 + tid;
    const int total = NPART * 256;

    int sidx[4], didx[4];
    #pragma unroll
    for (int it = 0; it < 4; ++it) {
        const int e  = gtid + it * total;
        const int ee = (e < E) ? e : (E - 1);
        sidx[it] = ei[ee];
        didx[it] = ei[E + ee];
    }

    float lsum = 0.f;
    #pragma unroll
    for (int it = 0; it < 4; ++it) {
        const int e = gtid + it * total;
        if (e < E) {
            float v = edge_ex(qtab[sidx[it]], ktab[didx[it]], W, cx);
            __half h = __float2half(v);
            exh[e] = h;
            lsum += __half2float(h);   // sum the rounded value
        }
    }

    red[tid] = lsum;
    __syncthreads();
    #pragma unroll
    for (int s = 128; s > 0; s >>= 1) {
        if (tid < s) red[tid] += red[tid + s];
        __syncthreads();
    }
    if (tid == 0) partial[blockIdx.x] = red[0];
}

// ---------------------------------------------------------------------------
// K3: redundant deterministic reduce of NPART partials, then out = exh * inv
// (half8 reads -> 2x float4 writes).
// ---------------------------------------------------------------------------
__global__ __launch_bounds__(256) void normalize_out(
        const __half* __restrict__ exh, const float* __restrict__ partial,
        float* __restrict__ out, int E) {
    __shared__ float red[256];
    const int tid = threadIdx.x;
    float s = 0.f;
    #pragma unroll
    for (int k = 0; k < NPART / 256; ++k) s += partial[tid + k * 256];
    red[tid] = s;
    __syncthreads();
    #pragma unroll
    for (int st = 128; st > 0; st >>= 1) {
        if (tid < st) red[tid] += red[tid + st];
        __syncthreads();
    }
    const float inv = 1.f / red[0];

    const int nv8    = E >> 3;                   // groups of 8 halfs
    const int stride = (int)(gridDim.x * 256);
    const uint4* exh8 = reinterpret_cast<const uint4*>(exh);
    float4* out4 = reinterpret_cast<float4*>(out);
    for (int i = blockIdx.x * 256 + tid; i < nv8; i += stride) {
        uint4 hv = exh8[i];
        __half2 h0 = *reinterpret_cast<__half2*>(&hv.x);
        __half2 h1 = *reinterpret_cast<__half2*>(&hv.y);
        __half2 h2 = *reinterpret_cast<__half2*>(&hv.z);
        __half2 h3 = *reinterpret_cast<__half2*>(&hv.w);
        float2 f0 = __half22float2(h0);
        float2 f1 = __half22float2(h1);
        float2 f2 = __half22float2(h2);
        float2 f3 = __half22float2(h3);
        out4[2 * i]     = make_float4(f0.x * inv, f0.y * inv, f1.x * inv, f1.y * inv);
        out4[2 * i + 1] = make_float4(f2.x * inv, f2.y * inv, f3.x * inv, f3.y * inv);
    }
    const int tail = nv8 << 3;
    for (int e = tail + blockIdx.x * 256 + tid; e < E; e += stride)
        out[e] = __half2float(exh[e]) * inv;
}

extern "C" void kernel_launch(void* const* d_in, const int* in_sizes, int n_in,
                              void* d_out, int out_size, void* d_ws, size_t ws_size,
                              hipStream_t stream) {
    const float* feat = (const float*)d_in[0];
    const int*   ei   = (const int*)d_in[1];
    const float* Wq   = (const float*)d_in[2];
    const float* bq   = (const float*)d_in[3];
    const float* Wk   = (const float*)d_in[4];
    const float* bk   = (const float*)d_in[5];
    const float* qp   = (const float*)d_in[6];

    int D = in_sizes[2] / 4;          // 256
    int N = in_sizes[0] / D;          // 50000
    int E = in_sizes[1] / 2;          // 800000
    (void)D;

    float*  ws      = (float*)d_ws;
    float*  partial = ws;                          // NPART floats
    float*  qtab    = ws + NPART;                  // 4N floats (16B aligned)
    float*  ktab    = qtab + (size_t)N * 4;        // 4N floats
    __half* exh     = (__half*)(ktab + (size_t)N * 4);  // E halfs (16B aligned)
    float*  out     = (float*)d_out;

    node_qk<<<2048, 256, 0, stream>>>(feat, Wq, bq, Wk, bk, qtab, ktab, N);
    edge_attn<<<NPART, 256, 0, stream>>>(ei, (const float4*)qtab, (const float4*)ktab,
                                         qp, exh, partial, E);
    normalize_out<<<1024, 256, 0, stream>>>(exh, partial, out, E);
}

// Round 12
// 31.733 us; speedup vs baseline: 1.2582x; 1.0348x over previous
//
#include <hip/hip_runtime.h>
#include <hip/hip_fp16.h>
#include <math.h>

#define HALF_PI   1.57079632679489662f
#define INV_SQRT2 0.70710678118654752f
#define NPART     1024   // edge-kernel blocks; strided EPT=4 covers E <= 1048576

// DPP cross-lane move (VALU, no DS pipe). CTRL: 0x128=row_ror:8 (i^8 in row16),
// 0x141=row_half_mirror (i^7 in 8), 0x1B=quad[3,2,1,0] (i^3), 0xB1=quad[1,0,3,2] (i^1)
template<int CTRL>
__device__ __forceinline__ float dppf(float v) {
    return __int_as_float(__builtin_amdgcn_update_dpp(
        0, __float_as_int(v), CTRL, 0xF, 0xF, false));
}

// ---------------------------------------------------------------------------
// K1: node projections. TWO nodes per wave per iteration. Weight fragments
// preloaded (32 VGPRs). Cross-lane reduction now uses permlane{32,16}_swap
// (VALU) + DPP instead of DS-pipe shuffles: 10 DS ops/node -> 0.
// Swap semantics are runtime-probed (direction AND pairing distance); probe
// failure falls back to the proven __shfl_xor path. The probe's per-lane
// "got x-sum" flag directly gives the lane->output-index mapping.
// ---------------------------------------------------------------------------
__global__ __launch_bounds__(256) void node_qk(
        const float* __restrict__ feat,
        const float* __restrict__ Wq, const float* __restrict__ bq,
        const float* __restrict__ Wk, const float* __restrict__ bk,
        float* __restrict__ qtab, float* __restrict__ ktab, int N) {
    const int lane  = threadIdx.x & 63;
    const int wid   = (int)((blockIdx.x * blockDim.x + threadIdx.x) >> 6);
    const int nwid  = (int)((gridDim.x * blockDim.x) >> 6);

    const bool hi  = (lane & 32) != 0;
    const bool s16 = (lane & 16) != 0;
    const bool s8  = (lane & 8)  != 0;

    // ---- probe permlane swap semantics (once; wave-uniform branches) ----
    bool use_pl32 = false, use_pl16 = false;
    bool gx32 = !hi;    // fallback mapping: low half owns outputs 0-3
    bool gx16 = !s16;   // fallback mapping: s16=0 owns bit1=0 outputs
#if __has_builtin(__builtin_amdgcn_permlane32_swap)
    {
        float x = (float)lane, y = 2000.0f + (float)lane;
        auto r = __builtin_amdgcn_permlane32_swap(
            __float_as_uint(x), __float_as_uint(y), false, false);
        float ps = __uint_as_float(r[0]) + __uint_as_float(r[1]);
        float xs = (float)(lane + (lane ^ 32));
        bool ok = (ps == xs) || (ps == 4000.0f + xs);
        if (__all(ok)) { use_pl32 = true; gx32 = (ps == xs); }
    }
#endif
#if __has_builtin(__builtin_amdgcn_permlane16_swap)
    {
        float x = (float)lane, y = 2000.0f + (float)lane;
        auto r = __builtin_amdgcn_permlane16_swap(
            __float_as_uint(x), __float_as_uint(y), false, false);
        float ps = __uint_as_float(r[0]) + __uint_as_float(r[1]);
        float xs = (float)(lane + (lane ^ 16));
        bool ok = (ps == xs) || (ps == 4000.0f + xs);
        if (__all(ok)) { use_pl16 = true; gx16 = (ps == xs); }
    }
#endif
    // output index this lane's group computes (verified-mapping dependent)
    const int  dot  = (gx32 ? 0 : 4) + (gx16 ? 0 : 2) + (s8 ? 1 : 0);
    const float bias = (dot < 4) ? bq[dot] : bk[dot & 3];

    // preload weight fragments (32 VGPRs)
    float4 wq4[4], wk4[4];
    #pragma unroll
    for (int q = 0; q < 4; ++q) {
        wq4[q] = reinterpret_cast<const float4*>(Wq + q * 256)[lane];
        wk4[q] = reinterpret_cast<const float4*>(Wk + q * 256)[lane];
    }

    // multi-value reduce: acc[8] partials -> every lane holds its group's dot
    auto reduce8 = [&](float* acc) -> float {
        float accR[4];
        if (use_pl32) {
            #pragma unroll
            for (int j = 0; j < 4; ++j) {
                auto r = __builtin_amdgcn_permlane32_swap(
                    __float_as_uint(acc[j]), __float_as_uint(acc[j + 4]), false, false);
                accR[j] = __uint_as_float(r[0]) + __uint_as_float(r[1]);
            }
        } else {
            #pragma unroll
            for (int j = 0; j < 4; ++j) {
                float give = hi ? acc[j] : acc[j + 4];
                float r = __shfl_xor(give, 32, 64);
                accR[j] = (hi ? acc[j + 4] : acc[j]) + r;
            }
        }
        float a0, a1;
        if (use_pl16) {
#if __has_builtin(__builtin_amdgcn_permlane16_swap)
            auto r0 = __builtin_amdgcn_permlane16_swap(
                __float_as_uint(accR[0]), __float_as_uint(accR[2]), false, false);
            a0 = __uint_as_float(r0[0]) + __uint_as_float(r0[1]);
            auto r1 = __builtin_amdgcn_permlane16_swap(
                __float_as_uint(accR[1]), __float_as_uint(accR[3]), false, false);
            a1 = __uint_as_float(r1[0]) + __uint_as_float(r1[1]);
#else
            a0 = 0.f; a1 = 0.f;
#endif
        } else {
            float give0 = s16 ? accR[0] : accR[2];
            float r0 = __shfl_xor(give0, 16, 64);
            a0 = (s16 ? accR[2] : accR[0]) + r0;
            float give1 = s16 ? accR[1] : accR[3];
            float r1 = __shfl_xor(give1, 16, 64);
            a1 = (s16 ? accR[3] : accR[1]) + r1;
        }
        // round 3: exact i^8 exchange via DPP row_ror:8
        float give3 = s8 ? a0 : a1;
        float r3 = dppf<0x128>(give3);
        float v = (s8 ? a1 : a0) + r3;
        // rounds 4-6: pure sum within 8-lane group (involutions 7,3,1)
        v += dppf<0x141>(v);
        v += dppf<0x1B>(v);
        v += dppf<0xB1>(v);
        return v;
    };

    for (int nb = wid * 2; nb < N; nb += nwid * 2) {
        const int n1ok = (nb + 1 < N);
        float4 f0 = reinterpret_cast<const float4*>(feat)[(size_t)nb * 64 + lane];
        float4 f1 = n1ok ? reinterpret_cast<const float4*>(feat)[(size_t)(nb + 1) * 64 + lane]
                         : make_float4(0.f, 0.f, 0.f, 0.f);

        float acc0[8], acc1[8];
        #pragma unroll
        for (int q = 0; q < 4; ++q) {
            acc0[q]     = f0.x * wq4[q].x + f0.y * wq4[q].y + f0.z * wq4[q].z + f0.w * wq4[q].w;
            acc0[4 + q] = f0.x * wk4[q].x + f0.y * wk4[q].y + f0.z * wk4[q].z + f0.w * wk4[q].w;
            acc1[q]     = f1.x * wq4[q].x + f1.y * wq4[q].y + f1.z * wq4[q].z + f1.w * wq4[q].w;
            acc1[4 + q] = f1.x * wk4[q].x + f1.y * wk4[q].y + f1.z * wk4[q].z + f1.w * wk4[q].w;
        }

        float v0 = reduce8(acc0);
        float v1 = reduce8(acc1);

        if ((lane & 7) == 0) {
            float t0 = tanhf(v0 + bias) * HALF_PI;
            if (dot < 4) qtab[(size_t)nb * 4 + dot] = t0;
            else         ktab[(size_t)nb * 4 + (dot & 3)] = t0;
            if (n1ok) {
                float t1 = tanhf(v1 + bias) * HALF_PI;
                if (dot < 4) qtab[(size_t)(nb + 1) * 4 + dot] = t1;
                else         ktab[(size_t)(nb + 1) * 4 + (dot & 3)] = t1;
            }
        }
    }
}

// ---------------------------------------------------------------------------
// 4-qubit real circuit. W[0..7] = pre-scaled Walsh weights for the Z part
// (attn_Z = sum_{x<8} W[x]*(a[x]^2 - a[15-x]^2), W[~x] = -W[x]); cx = pre-
// scaled X coefficients. 0.25 softmax scale folded into W/cx.
// ---------------------------------------------------------------------------
__device__ __forceinline__ float edge_ex(float4 qv, float4 kv,
                                         const float* W, const float* cx) {
    float u[4][2];
    {
        float qa[4] = {qv.x, qv.y, qv.z, qv.w};
        #pragma unroll
        for (int w = 0; w < 4; ++w) {
            float s, c;
            __sincosf(qa[w] * 0.5f, &s, &c);
            u[w][0] = (c + s) * INV_SQRT2;
            u[w][1] = (c - s) * INV_SQRT2;
        }
    }
    float c01[4] = {u[0][0]*u[1][0], u[0][0]*u[1][1], u[0][1]*u[1][0], u[0][1]*u[1][1]};
    float c23[4] = {u[2][0]*u[3][0], u[2][0]*u[3][1], u[2][1]*u[3][0], u[2][1]*u[3][1]};
    float a[16];
    #pragma unroll
    for (int x = 0; x < 16; ++x) a[x] = c01[x >> 2] * c23[x & 3];

    {
        float ka[4] = {kv.x, kv.y, kv.z, kv.w};
        #pragma unroll
        for (int w = 0; w < 4; ++w) {
            float si, co;
            __sincosf(ka[w] * 0.5f, &si, &co);
            const int cb = 1 << (3 - w);
            const int tb = 1 << (3 - ((w + 1) & 3));
            #pragma unroll
            for (int x = 0; x < 16; ++x) {
                if ((x & cb) && !(x & tb)) {
                    float a0 = a[x], a1 = a[x | tb];
                    a[x]      = co * a0 - si * a1;
                    a[x | tb] = si * a0 + co * a1;
                }
            }
        }
    }

    float attn = 0.f;
    #pragma unroll
    for (int x = 0; x < 8; ++x) {
        float pu = a[15 - x] * a[15 - x];
        float d  = __builtin_fmaf(a[x], a[x], -pu);
        attn = __builtin_fmaf(W[x], d, attn);
    }
    #pragma unroll
    for (int q = 0; q < 4; ++q) {
        const int bit = 1 << (3 - q);
        float sx = 0.f;
        #pragma unroll
        for (int x = 0; x < 16; ++x)
            if (!(x & bit)) sx = __builtin_fmaf(a[x], a[x | bit], sx);
        attn = __builtin_fmaf(cx[q], sx, attn);
    }
    return __expf(attn);
}

// ---------------------------------------------------------------------------
// K2: per-edge circuit, STRIDED 4 edges/thread. Index loads prefetched;
// gathers inline. Stores fp16 ex; partials sum the ROUNDED values.
// ---------------------------------------------------------------------------
__global__ __launch_bounds__(256) void edge_attn(
        const int* __restrict__ ei,
        const float4* __restrict__ qtab, const float4* __restrict__ ktab,
        const float* __restrict__ qp,
        __half* __restrict__ exh, float* __restrict__ partial, int E) {
    __shared__ float scz[4], scxs[4];
    __shared__ float red[256];
    const int tid = threadIdx.x;
    if (tid < 4) {
        float phi = qp[3 * tid + 0];
        float th  = qp[3 * tid + 1];
        float sth, cth;
        sincosf(th, &sth, &cth);
        scz[tid]  = 0.25f * cth;
        scxs[tid] = -0.5f * sth * cosf(phi);
    }
    __syncthreads();

    const float z0 = scz[0], z1 = scz[1], z2 = scz[2], z3 = scz[3];
    const float u0 = z2 + z3, u1 = z2 - z3;
    const float w00 = z1 + u0, w01 = z1 + u1, w10 = z1 - u1, w11 = z1 - u0;
    const float W[8] = {z0 + w00, z0 + w01, z0 + w10, z0 + w11,
                        z0 - w11, z0 - w10, z0 - w01, z0 - w00};
    const float cx[4] = {scxs[0], scxs[1], scxs[2], scxs[3]};

    const int gtid  = blockIdx.x * 256 + tid;
    const int total = NPART * 256;

    int sidx[4], didx[4];
    #pragma unroll
    for (int it = 0; it < 4; ++it) {
        const int e  = gtid + it * total;
        const int ee = (e < E) ? e : (E - 1);
        sidx[it] = ei[ee];
        didx[it] = ei[E + ee];
    }

    float lsum = 0.f;
    #pragma unroll
    for (int it = 0; it < 4; ++it) {
        const int e = gtid + it * total;
        if (e < E) {
            float v = edge_ex(qtab[sidx[it]], ktab[didx[it]], W, cx);
            __half h = __float2half(v);
            exh[e] = h;
            lsum += __half2float(h);
        }
    }

    red[tid] = lsum;
    __syncthreads();
    #pragma unroll
    for (int s = 128; s > 0; s >>= 1) {
        if (tid < s) red[tid] += red[tid + s];
        __syncthreads();
    }
    if (tid == 0) partial[blockIdx.x] = red[0];
}

// ---------------------------------------------------------------------------
// K3: redundant deterministic reduce of NPART partials, then out = exh * inv.
// ---------------------------------------------------------------------------
__global__ __launch_bounds__(256) void normalize_out(
        const __half* __restrict__ exh, const float* __restrict__ partial,
        float* __restrict__ out, int E) {
    __shared__ float red[256];
    const int tid = threadIdx.x;
    float s = 0.f;
    #pragma unroll
    for (int k = 0; k < NPART / 256; ++k) s += partial[tid + k * 256];
    red[tid] = s;
    __syncthreads();
    #pragma unroll
    for (int st = 128; st > 0; st >>= 1) {
        if (tid < st) red[tid] += red[tid + st];
        __syncthreads();
    }
    const float inv = 1.f / red[0];

    const int nv8    = E >> 3;
    const int stride = (int)(gridDim.x * 256);
    const uint4* exh8 = reinterpret_cast<const uint4*>(exh);
    float4* out4 = reinterpret_cast<float4*>(out);
    for (int i = blockIdx.x * 256 + tid; i < nv8; i += stride) {
        uint4 hv = exh8[i];
        __half2 h0 = *reinterpret_cast<__half2*>(&hv.x);
        __half2 h1 = *reinterpret_cast<__half2*>(&hv.y);
        __half2 h2 = *reinterpret_cast<__half2*>(&hv.z);
        __half2 h3 = *reinterpret_cast<__half2*>(&hv.w);
        float2 f0 = __half22float2(h0);
        float2 f1 = __half22float2(h1);
        float2 f2 = __half22float2(h2);
        float2 f3 = __half22float2(h3);
        out4[2 * i]     = make_float4(f0.x * inv, f0.y * inv, f1.x * inv, f1.y * inv);
        out4[2 * i + 1] = make_float4(f2.x * inv, f2.y * inv, f3.x * inv, f3.y * inv);
    }
    const int tail = nv8 << 3;
    for (int e = tail + blockIdx.x * 256 + tid; e < E; e += stride)
        out[e] = __half2float(exh[e]) * inv;
}

extern "C" void kernel_launch(void* const* d_in, const int* in_sizes, int n_in,
                              void* d_out, int out_size, void* d_ws, size_t ws_size,
                              hipStream_t stream) {
    const float* feat = (const float*)d_in[0];
    const int*   ei   = (const int*)d_in[1];
    const float* Wq   = (const float*)d_in[2];
    const float* bq   = (const float*)d_in[3];
    const float* Wk   = (const float*)d_in[4];
    const float* bk   = (const float*)d_in[5];
    const float* qp   = (const float*)d_in[6];

    int D = in_sizes[2] / 4;          // 256
    int N = in_sizes[0] / D;          // 50000
    int E = in_sizes[1] / 2;          // 800000
    (void)D;

    float*  ws      = (float*)d_ws;
    float*  partial = ws;                          // NPART floats
    float*  qtab    = ws + NPART;                  // 4N floats (16B aligned)
    float*  ktab    = qtab + (size_t)N * 4;        // 4N floats
    __half* exh     = (__half*)(ktab + (size_t)N * 4);  // E halfs (16B aligned)
    float*  out     = (float*)d_out;

    node_qk<<<2048, 256, 0, stream>>>(feat, Wq, bq, Wk, bk, qtab, ktab, N);
    edge_attn<<<NPART, 256, 0, stream>>>(ei, (const float4*)qtab, (const float4*)ktab,
                                         qp, exh, partial, E);
    normalize_out<<<1024, 256, 0, stream>>>(exh, partial, out, E);
}